// Round 3
// baseline (356.498 us; speedup 1.0000x reference)
//
#include <hip/hip_runtime.h>
#include <hip/hip_cooperative_groups.h>
#include <stdint.h>

namespace cg = cooperative_groups;

// MarginLoss: loss = mean(max(logits - logits[argmax(labels)] + margin, eps))
// labels one-hot -> argmax == position of the unique nonzero.
// Mandatory traffic: 256 MiB labels + 256 MiB logits = 512 MiB read.
// Harness fill kernels demonstrate ~6.96 TB/s (87% peak) -> ~77 us floor.
// Single cooperative kernel: scan labels -> grid.sync -> clamped sum ->
// grid.sync -> block-0 finalize. One launch, no inter-kernel gaps.

static constexpr int BLOCK = 256;
static constexpr int GRID  = 1024;   // 4 blocks/CU: co-residency guaranteed

#define MARGIN_F 1.0f
#define EPS_F    1e-6f

typedef int   v4i __attribute__((ext_vector_type(4)));
typedef float v4f __attribute__((ext_vector_type(4)));

// ---------------- shared device bodies (used by fused + fallback) ----------

__device__ __forceinline__ void scan_labels_body(
        const int* __restrict__ labels, const float* __restrict__ logits,
        int n, float* __restrict__ s_out) {
    const int n4     = n >> 2;
    const int stride = (int)(gridDim.x * blockDim.x);
    int i = (int)(blockIdx.x * blockDim.x + threadIdx.x);
    const v4i* __restrict__ l4 = (const v4i*)labels;

#define ORV(v) ((v).x | (v).y | (v).z | (v).w)
#define CHECKG(v, ii)                                                        \
    if (ORV(v)) {                                                            \
        int base_ = (ii) << 2;                                               \
        int j_ = (v).x ? 0 : ((v).y ? 1 : ((v).z ? 2 : 3));                  \
        s_out[0] = logits[base_ + j_];                                       \
    }

    for (; i + 7 * stride < n4; i += 8 * stride) {
        v4i a = l4[i];
        v4i b = l4[i + stride];
        v4i c = l4[i + 2 * stride];
        v4i d = l4[i + 3 * stride];
        v4i e = l4[i + 4 * stride];
        v4i f = l4[i + 5 * stride];
        v4i g = l4[i + 6 * stride];
        v4i h = l4[i + 7 * stride];
        int any = ORV(a) | ORV(b) | ORV(c) | ORV(d)
                | ORV(e) | ORV(f) | ORV(g) | ORV(h);
        if (any) {                      // cold: taken by at most one int4 run
            CHECKG(a, i);
            CHECKG(b, i + stride);
            CHECKG(c, i + 2 * stride);
            CHECKG(d, i + 3 * stride);
            CHECKG(e, i + 4 * stride);
            CHECKG(f, i + 5 * stride);
            CHECKG(g, i + 6 * stride);
            CHECKG(h, i + 7 * stride);
        }
    }
    for (; i < n4; i += stride) {
        v4i a = l4[i];
        CHECKG(a, i);
    }
    if (blockIdx.x == 0) {              // scalar tail (empty for n = 2^26)
        for (int j = (n4 << 2) + (int)threadIdx.x; j < n; j += (int)blockDim.x)
            if (labels[j]) s_out[0] = logits[j];
    }
#undef CHECKG
#undef ORV
}

__device__ __forceinline__ float clamped_partial_body(
        const float* __restrict__ logits, int n, float c) {
    const int n4     = n >> 2;
    const int stride = (int)(gridDim.x * blockDim.x);
    int i = (int)(blockIdx.x * blockDim.x + threadIdx.x);
    const v4f* __restrict__ l4 = (const v4f*)logits;

    float p0 = 0.f, p1 = 0.f, p2 = 0.f, p3 = 0.f;
    float p4 = 0.f, p5 = 0.f, p6 = 0.f, p7 = 0.f;

#define ACC(p, v)                                                            \
    p += fmaxf((v).x + c, EPS_F) + fmaxf((v).y + c, EPS_F)                   \
       + fmaxf((v).z + c, EPS_F) + fmaxf((v).w + c, EPS_F)

    for (; i + 7 * stride < n4; i += 8 * stride) {
        v4f a = l4[i];
        v4f b = l4[i + stride];
        v4f cc = l4[i + 2 * stride];
        v4f d = l4[i + 3 * stride];
        v4f e = l4[i + 4 * stride];
        v4f f = l4[i + 5 * stride];
        v4f g = l4[i + 6 * stride];
        v4f h = l4[i + 7 * stride];
        ACC(p0, a); ACC(p1, b); ACC(p2, cc); ACC(p3, d);
        ACC(p4, e); ACC(p5, f); ACC(p6, g);  ACC(p7, h);
    }
    for (; i < n4; i += stride) {
        v4f a = l4[i];
        ACC(p0, a);
    }
#undef ACC
    if (blockIdx.x == 0) {              // scalar tail (empty for n = 2^26)
        for (int j = (n4 << 2) + (int)threadIdx.x; j < n; j += (int)blockDim.x)
            p0 += fmaxf(logits[j] + c, EPS_F);
    }
    return ((p0 + p1) + (p2 + p3)) + ((p4 + p5) + (p6 + p7));
}

// valid on threadIdx.x == 0 only
__device__ __forceinline__ float block_reduce_sum(float v) {
    #pragma unroll
    for (int off = 32; off > 0; off >>= 1)
        v += __shfl_down(v, off, 64);
    __shared__ float sm[BLOCK / 64];
    const int lane = threadIdx.x & 63;
    const int wv   = threadIdx.x >> 6;
    if (lane == 0) sm[wv] = v;
    __syncthreads();
    float r = 0.f;
    if (threadIdx.x == 0) {
        #pragma unroll
        for (int w = 0; w < BLOCK / 64; ++w) r += sm[w];
    }
    return r;
}

// ---------------- fused cooperative kernel ---------------------------------

__global__ __launch_bounds__(BLOCK, 4) void fused_kernel(
        const float* __restrict__ logits, const int* __restrict__ labels,
        int n_logits, int n_labels,
        float* __restrict__ partials, float* __restrict__ s_ws,
        float* __restrict__ out) {
    cg::grid_group grid = cg::this_grid();

    scan_labels_body(labels, logits, n_labels, s_ws);
    grid.sync();

    const float c = MARGIN_F - s_ws[0];
    float partial = clamped_partial_body(logits, n_logits, c);
    float bsum = block_reduce_sum(partial);
    if (threadIdx.x == 0) partials[blockIdx.x] = bsum;
    grid.sync();

    if (blockIdx.x == 0) {
        double s = 0.0;
        for (int j = threadIdx.x; j < GRID; j += BLOCK)
            s += (double)partials[j];
        #pragma unroll
        for (int off = 32; off > 0; off >>= 1)
            s += __shfl_down(s, off, 64);
        __shared__ double smd[BLOCK / 64];
        const int lane = threadIdx.x & 63;
        const int wv   = threadIdx.x >> 6;
        if (lane == 0) smd[wv] = s;
        __syncthreads();
        if (threadIdx.x == 0) {
            double t = 0.0;
            #pragma unroll
            for (int w = 0; w < BLOCK / 64; ++w) t += smd[w];
            out[0] = (float)(t / (double)n_logits);
        }
    }
}

// ---------------- non-cooperative fallback ---------------------------------

__global__ __launch_bounds__(BLOCK) void scan_kernel(
        const int* __restrict__ labels, const float* __restrict__ logits,
        int n, float* __restrict__ s_ws) {
    scan_labels_body(labels, logits, n, s_ws);
}

__global__ __launch_bounds__(BLOCK) void sum_kernel(
        const float* __restrict__ logits, int n,
        const float* __restrict__ s_ws, float* __restrict__ partials) {
    const float c = MARGIN_F - s_ws[0];
    float partial = clamped_partial_body(logits, n, c);
    float bsum = block_reduce_sum(partial);
    if (threadIdx.x == 0) partials[blockIdx.x] = bsum;
}

__global__ __launch_bounds__(BLOCK) void finalize_kernel(
        const float* __restrict__ partials, float* __restrict__ out, int n) {
    double s = 0.0;
    for (int j = threadIdx.x; j < GRID; j += BLOCK)
        s += (double)partials[j];
    #pragma unroll
    for (int off = 32; off > 0; off >>= 1)
        s += __shfl_down(s, off, 64);
    __shared__ double smd[BLOCK / 64];
    const int lane = threadIdx.x & 63;
    const int wv   = threadIdx.x >> 6;
    if (lane == 0) smd[wv] = s;
    __syncthreads();
    if (threadIdx.x == 0) {
        double t = 0.0;
        #pragma unroll
        for (int w = 0; w < BLOCK / 64; ++w) t += smd[w];
        out[0] = (float)(t / (double)n);
    }
}

// ---------------- launch ---------------------------------------------------

extern "C" void kernel_launch(void* const* d_in, const int* in_sizes, int n_in,
                              void* d_out, int out_size, void* d_ws, size_t ws_size,
                              hipStream_t stream) {
    const float* logits = (const float*)d_in[0];
    const int*   labels = (const int*)d_in[1];
    int n_logits = in_sizes[0];
    int n_labels = in_sizes[1];

    float* partials = (float*)d_ws;
    float* s_ws     = (float*)((char*)d_ws + GRID * sizeof(float));
    float* out      = (float*)d_out;

    void* args[] = {(void*)&logits, (void*)&labels, (void*)&n_logits,
                    (void*)&n_labels, (void*)&partials, (void*)&s_ws,
                    (void*)&out};
    hipError_t err = hipLaunchCooperativeKernel(
        reinterpret_cast<void*>(fused_kernel), dim3(GRID), dim3(BLOCK),
        args, 0, stream);

    if (err != hipSuccess) {
        (void)hipGetLastError();   // clear sticky error, use plain path
        scan_kernel<<<GRID, BLOCK, 0, stream>>>(labels, logits, n_labels, s_ws);
        sum_kernel<<<GRID, BLOCK, 0, stream>>>(logits, n_logits, s_ws, partials);
        finalize_kernel<<<1, BLOCK, 0, stream>>>(partials, out, n_logits);
    }
}